// Round 1
// 1503.627 us; speedup vs baseline: 1.0239x; 1.0239x over previous
//
#include <hip/hip_runtime.h>
#include <hip/hip_bf16.h>
#include <cmath>

// ---------------------------------------------------------------------------
// MoE "pure field": gate(softmax@T=e, top-5/8, renorm, sign) + dense 2-layer
// FFN over all experts, accumulated with signed gate weights.
//   N=8192, D_IN=1024, D_HID=4096, D_OUT=1024, E=8, k=5
// Round 4: 8-phase 256x256xBK64 schedule (T2 swizzle + T3/T4 counted vmcnt +
//   T5 setprio) for GEMM1 always and for GEMM2 when ws >= NEED_MID (252MB,
//   split-K=2 per expert into out + P1). Fallback GEMM2 = round-3 gemm_acc.
// ---------------------------------------------------------------------------

typedef _Float16 f16;
typedef _Float16 f16x8 __attribute__((ext_vector_type(8)));
typedef _Float16 f16x4 __attribute__((ext_vector_type(4)));
typedef float f32x4 __attribute__((ext_vector_type(4)));

#define NROWS 8192
#define DIN   1024
#define DHID  4096
#define DOUT  1024
#define NEXP  8

// workspace layout (bytes)
#define OFF_SGATE 0u
#define OFF_XH    262144u          // xh: 8192x1024 f16 = 16MB
#define OFF_W1T   17039360u        // w1t: 8x4096x1024 f16 = 64MB
#define OFF_W2T   84148224u        // w2t: 8x1024x4096 f16 = 64MB
#define OFF_HHS   151257088u       // hh: 8192x4096 f16 = 64MB (one expert)
#define OFF_P1    218365952u       // mid tier only: P1 partial f32 = 32MB
#define NEED_MID  251920384ull

__device__ __forceinline__ void gload_lds16(const void* gsrc, void* ldsdst) {
  __builtin_amdgcn_global_load_lds(
      (const __attribute__((address_space(1))) unsigned int*)gsrc,
      (__attribute__((address_space(3))) unsigned int*)ldsdst, 16, 0, 0);
}

// ---------------------------------------------------------------------------
// Gate (unchanged, proven).
// ---------------------------------------------------------------------------
__global__ void gate_kernel(const float* __restrict__ x,
                            const float* __restrict__ gw,
                            const float* __restrict__ gb,
                            float* __restrict__ sgate) {
  const int row = blockIdx.x * 4 + (threadIdx.x >> 6);
  const int l = threadIdx.x & 63;
  const float* xr = x + (size_t)row * DIN;
  float acc[8] = {0.f,0.f,0.f,0.f,0.f,0.f,0.f,0.f};
#pragma unroll
  for (int j = 0; j < 16; ++j) {
    const int k = l + 64 * j;
    const float xv = xr[k];
    const float4 g0 = *(const float4*)(gw + (size_t)k * 8);
    const float4 g1 = *(const float4*)(gw + (size_t)k * 8 + 4);
    acc[0] += xv * g0.x; acc[1] += xv * g0.y; acc[2] += xv * g0.z; acc[3] += xv * g0.w;
    acc[4] += xv * g1.x; acc[5] += xv * g1.y; acc[6] += xv * g1.z; acc[7] += xv * g1.w;
  }
#pragma unroll
  for (int off = 32; off > 0; off >>= 1) {
#pragma unroll
    for (int e = 0; e < 8; ++e) acc[e] += __shfl_xor(acc[e], off, 64);
  }
  if (l == 0) {
    const float invT = 0.36787944117144233f;
    float p[8]; float mx = -1e30f;
#pragma unroll
    for (int e = 0; e < 8; ++e) { p[e] = (acc[e] + gb[e]) * invT; mx = fmaxf(mx, p[e]); }
    float S = 0.f;
#pragma unroll
    for (int e = 0; e < 8; ++e) { p[e] = expf(p[e] - mx); S += p[e]; }
    const float inv = 1.0f / S;
#pragma unroll
    for (int e = 0; e < 8; ++e) p[e] *= inv;
    bool keep[8] = {true,true,true,true,true,true,true,true};
    for (int t = 0; t < 3; ++t) {
      float pmin = 1e30f; int mi = -1;
      for (int e = 0; e < 8; ++e)
        if (keep[e] && (p[e] < pmin || (p[e] == pmin && e > mi))) { pmin = p[e]; mi = e; }
      keep[mi] = false;
    }
    float wsum = 0.f;
#pragma unroll
    for (int e = 0; e < 8; ++e) if (keep[e]) wsum += p[e];
    const float rinv = 1.0f / (wsum + 1e-8f);
#pragma unroll
    for (int e = 0; e < 8; ++e) {
      const float wv = keep[e] ? p[e] * rinv : 0.0f;
      sgate[(size_t)row * 8 + e] = (e < 4) ? wv : -wv;
    }
  }
}

__global__ void cvt_x_kernel(const float* __restrict__ x, f16* __restrict__ xh) {
  const size_t i = ((size_t)blockIdx.x * blockDim.x + threadIdx.x) * 4;
  const float4 v = *(const float4*)(x + i);
  f16x4 o = { (f16)v.x, (f16)v.y, (f16)v.z, (f16)v.w };
  *(f16x4*)(xh + i) = o;
}

// in f32 [E][R][C] -> out fp16 [E][C][R]
__global__ void transpose_cvt(const float* __restrict__ in, f16* __restrict__ out,
                              int R, int C) {
  __shared__ float tile[32][33];
  const int e = blockIdx.z;
  const float* ine = in + (size_t)e * R * C;
  f16* oute = out + (size_t)e * R * C;
  const int c0 = blockIdx.x * 32, r0 = blockIdx.y * 32;
  const int tx = threadIdx.x, ty = threadIdx.y;
#pragma unroll
  for (int i = 0; i < 4; ++i)
    tile[ty + i * 8][tx] = ine[(size_t)(r0 + ty + i * 8) * C + c0 + tx];
  __syncthreads();
#pragma unroll
  for (int i = 0; i < 4; ++i)
    oute[(size_t)(c0 + ty + i * 8) * R + r0 + tx] = (f16)tile[tx][ty + i * 8];
}

#define MFMAOP(a_, b_, c_) __builtin_amdgcn_mfma_f32_16x16x32_f16(a_, b_, c_, 0, 0, 0)

// ---------------------------------------------------------------------------
// gemm8p: 8-phase 256x256 BK=64 schedule (HK-style, guide-verified template).
//   C = A[M,K] x B[rows,K]^T. 512 thr = 8 waves (2M x 4N), wave tile 128x64.
//   LDS = 4 half-tile slots per operand (4 x 128x64 f16 = 64KB each) = 128KB.
//   Per K-tile: 4 phases, each {ds-read subtile | stage 1 half-tile (2
//   gload_lds) | barrier | lgkmcnt(0) | setprio(1) 16 MFMA setprio(0) |
//   barrier}. vmcnt(6) ONCE per K-tile (phase 3) -> 3 half-tiles in flight.
//   Stage schedule per tile t: p0: B1(t+1), p2: B0(t+2), p3: A0+A1(t+2).
//   Ledger: carry-in 3 halves of t+1; vmcnt(6)@p3 proves tile t+1 complete.
//   Slot safety: stages into current-parity slots issue only after that
//   slot's last ds_read phase has barrier-completed (A read @p0,p2 ->
//   staged @p3; B read @p0,p1 -> staged @p2).
//   Swizzle (128B rows, 8 chunks): LDS(r,c) = G(r, c^(r&7)); applied on the
//   pre-swizzled global source (linear gload_lds dest) and on ds_read offs.
// EPI=1: outH[row][n0+col] = f16( sg[row,e] * relu(acc + bias[col]) )
// EPI=2: split-K: kh = lg&1 selects K-half (+2048 cols) and P0(out)/P1;
//        p1w -> write, else RMW accumulate (expert-sequential, race-free).
// ---------------------------------------------------------------------------
template <int EPI>
__global__ __launch_bounds__(512, 2) void gemm8p(
    const f16* __restrict__ A, int lda,
    const f16* __restrict__ B, int ldb, int nt,
    const float* __restrict__ bias,
    f16* __restrict__ outH, int ldc,
    float* outP0, float* outP1, int p1w,
    const float* __restrict__ sgate, int expert, int gx) {
  __shared__ alignas(16) f16 lA[4 * 8192];   // 4 slots x 16KB
  __shared__ alignas(16) f16 lB[4 * 8192];
  const int tid = threadIdx.x;
  const int l = tid & 63, w = tid >> 6;
  const int wr = w >> 2, wc = w & 3;

  // T1 XCD swizzle (grid % 8 == 0 in all launches)
  const int nwg = gridDim.x, cpx = nwg >> 3;
  const int lg = ((int)blockIdx.x & 7) * cpx + ((int)blockIdx.x >> 3);

  int m0, n0;
  const f16* Aeff = A;
  const f16* Beff = B;
  float* P = nullptr;
  bool pw = false;
  if constexpr (EPI == 1) {
    m0 = (lg / gx) * 256; n0 = (lg % gx) * 256;
  } else {
    const int kh = lg & 1;
    const int tt = lg >> 1;
    m0 = (tt / gx) * 256; n0 = (tt % gx) * 256;
    Aeff = A + kh * 2048;
    Beff = B + kh * 2048;
    P = kh ? outP1 : outP0;
    pw = (p1w != 0);
  }

  // staging: thread -> (row tid>>3, chunk tid&7); source chunk pre-swizzled
  const int srow = tid >> 3;
  const int sxc = (tid & 7) ^ (srow & 7);
  const f16* pA = Aeff + (size_t)(m0 + srow) * lda + sxc * 8;
  const f16* pB = Beff + (size_t)(n0 + srow) * ldb + sxc * 8;
  f16* const dA = lA + w * 512;   // wave-uniform LDS base (+ lane*16B by HW)
  f16* const dB = lB + w * 512;

#define STG_A(slot, h, tk) do { \
    const f16* s_ = pA + (size_t)(h) * 128 * lda + (size_t)(tk) * 64; \
    gload_lds16(s_,            dA + (slot) * 8192); \
    gload_lds16(s_ + 64 * lda, dA + (slot) * 8192 + 4096); \
  } while (0)
#define STG_B(slot, h, tk) do { \
    const f16* s_ = pB + (size_t)(h) * 128 * ldb + (size_t)(tk) * 64; \
    gload_lds16(s_,            dB + (slot) * 8192); \
    gload_lds16(s_ + 64 * ldb, dB + (slot) * 8192 + 4096); \
  } while (0)

  // ds_read fragment offsets (bytes), same xor involution as the source
  const int cg = l >> 4, xr = l & 7;
  const int ok0 = ((cg ^ xr) << 4);
  const int ok1 = (((4 + cg) ^ xr) << 4);
  const char* const baA = (const char*)lA + (l & 15) * 128;
  const char* const baB = (const char*)lB + (wc & 1) * 8192 + (l & 15) * 128;

#define RDA(CA, f, o) (*(const f16x8*)(baA + ((CA) + wr) * 16384 + (f) * 2048 + (o)))
#define RDB(CB, g, o) (*(const f16x8*)(baB + ((CB) + (wc >> 1)) * 16384 + (g) * 2048 + (o)))
#define SYNC() do { __builtin_amdgcn_s_barrier(); \
    asm volatile("s_waitcnt lgkmcnt(0)" ::: "memory"); \
    __builtin_amdgcn_sched_barrier(0); } while (0)
#define ENDPH() do { __builtin_amdgcn_s_setprio(0); \
    __builtin_amdgcn_s_barrier(); } while (0)
#define VM6() do { asm volatile("s_waitcnt vmcnt(6)" ::: "memory"); \
    __builtin_amdgcn_sched_barrier(0); } while (0)
#define MM(f, g, ar, br) acc[f][g] = MFMAOP(ar, br, acc[f][g])

  f32x4 acc[8][4] = {};
  f16x8 aA0,aA1,aB0,aB1,aC0,aC1,aD0,aD1;   // 4 m-frags x 2 kslices (reused)
  f16x8 b00,b01,b10,b11,b20,b21,b30,b31;   // 4 n-frags x 2 kslices

#define TILEBODY(T, CA, CB, SB1, SB0n, SA0n, SA1n) do { \
    /* phase 0: f0-3 x g0-1 */ \
    aA0 = RDA(CA, 0, ok0); aA1 = RDA(CA, 0, ok1); \
    aB0 = RDA(CA, 1, ok0); aB1 = RDA(CA, 1, ok1); \
    aC0 = RDA(CA, 2, ok0); aC1 = RDA(CA, 2, ok1); \
    aD0 = RDA(CA, 3, ok0); aD1 = RDA(CA, 3, ok1); \
    b00 = RDB(CB, 0, ok0); b01 = RDB(CB, 0, ok1); \
    b10 = RDB(CB, 1, ok0); b11 = RDB(CB, 1, ok1); \
    if ((T) + 1 < nt) STG_B(SB1, 1, (T) + 1); \
    SYNC(); \
    __builtin_amdgcn_s_setprio(1); \
    MM(0,0,aA0,b00); MM(0,1,aA0,b10); MM(1,0,aB0,b00); MM(1,1,aB0,b10); \
    MM(2,0,aC0,b00); MM(2,1,aC0,b10); MM(3,0,aD0,b00); MM(3,1,aD0,b10); \
    MM(0,0,aA1,b01); MM(0,1,aA1,b11); MM(1,0,aB1,b01); MM(1,1,aB1,b11); \
    MM(2,0,aC1,b01); MM(2,1,aC1,b11); MM(3,0,aD1,b01); MM(3,1,aD1,b11); \
    ENDPH(); \
    /* phase 1: f0-3 x g2-3 */ \
    b20 = RDB(CB, 2, ok0); b21 = RDB(CB, 2, ok1); \
    b30 = RDB(CB, 3, ok0); b31 = RDB(CB, 3, ok1); \
    SYNC(); \
    __builtin_amdgcn_s_setprio(1); \
    MM(0,2,aA0,b20); MM(0,3,aA0,b30); MM(1,2,aB0,b20); MM(1,3,aB0,b30); \
    MM(2,2,aC0,b20); MM(2,3,aC0,b30); MM(3,2,aD0,b20); MM(3,3,aD0,b30); \
    MM(0,2,aA1,b21); MM(0,3,aA1,b31); MM(1,2,aB1,b21); MM(1,3,aB1,b31); \
    MM(2,2,aC1,b21); MM(2,3,aC1,b31); MM(3,2,aD1,b21); MM(3,3,aD1,b31); \
    ENDPH(); \
    /* phase 2: f4-7 x g0-1 */ \
    aA0 = RDA(CA, 4, ok0); aA1 = RDA(CA, 4, ok1); \
    aB0 = RDA(CA, 5, ok0); aB1 = RDA(CA, 5, ok1); \
    aC0 = RDA(CA, 6, ok0); aC1 = RDA(CA, 6, ok1); \
    aD0 = RDA(CA, 7, ok0); aD1 = RDA(CA, 7, ok1); \
    if ((T) + 2 < nt) STG_B(SB0n, 0, (T) + 2); \
    SYNC(); \
    __builtin_amdgcn_s_setprio(1); \
    MM(4,0,aA0,b00); MM(4,1,aA0,b10); MM(5,0,aB0,b00); MM(5,1,aB0,b10); \
    MM(6,0,aC0,b00); MM(6,1,aC0,b10); MM(7,0,aD0,b00); MM(7,1,aD0,b10); \
    MM(4,0,aA1,b01); MM(4,1,aA1,b11); MM(5,0,aB1,b01); MM(5,1,aB1,b11); \
    MM(6,0,aC1,b01); MM(6,1,aC1,b11); MM(7,0,aD1,b01); MM(7,1,aD1,b11); \
    ENDPH(); \
    /* phase 3: f4-7 x g2-3 */ \
    if ((T) + 2 < nt) { STG_A(SA0n, 0, (T) + 2); STG_A(SA1n, 1, (T) + 2); } \
    VM6(); \
    SYNC(); \
    __builtin_amdgcn_s_setprio(1); \
    MM(4,2,aA0,b20); MM(4,3,aA0,b30); MM(5,2,aB0,b20); MM(5,3,aB0,b30); \
    MM(6,2,aC0,b20); MM(6,3,aC0,b30); MM(7,2,aD0,b20); MM(7,3,aD0,b30); \
    MM(4,2,aA1,b21); MM(4,3,aA1,b31); MM(5,2,aB1,b21); MM(5,3,aB1,b31); \
    MM(6,2,aC1,b21); MM(6,3,aC1,b31); MM(7,2,aD1,b21); MM(7,3,aD1,b31); \
    ENDPH(); \
  } while (0)

  // prologue: tile0 (A0,B0,A1,B1) + tile1 (A0,B0,A1); 14 loads, drain to 6
  STG_A(0, 0, 0); STG_B(0, 0, 0); STG_A(1, 1, 0); STG_B(1, 1, 0);
  STG_A(2, 0, 1); STG_B(2, 0, 1); STG_A(3, 1, 1);
  asm volatile("s_waitcnt vmcnt(6)" ::: "memory");
  __builtin_amdgcn_s_barrier();

  for (int t = 0; t < nt; t += 2) {
    TILEBODY(t,     0, 0, 3, 0, 0, 1);
    TILEBODY(t + 1, 2, 2, 1, 2, 2, 3);
  }
  asm volatile("s_waitcnt vmcnt(0)" ::: "memory");

  // epilogue
  if constexpr (EPI == 1) {
#pragma unroll
    for (int mi = 0; mi < 8; ++mi)
#pragma unroll
      for (int r = 0; r < 4; ++r) {
        const int row = m0 + wr * 128 + mi * 16 + (l >> 4) * 4 + r;
        const float sg = sgate[(size_t)row * 8 + expert];
#pragma unroll
        for (int ni = 0; ni < 4; ++ni) {
          const int col = n0 + wc * 64 + ni * 16 + (l & 15);
          const float v = acc[mi][ni][r] + bias[col];
          outH[(size_t)row * ldc + col] = (f16)(fmaxf(v, 0.0f) * sg);
        }
      }
  } else {
#pragma unroll
    for (int mi = 0; mi < 8; ++mi)
#pragma unroll
      for (int r = 0; r < 4; ++r) {
        const int row = m0 + wr * 128 + mi * 16 + (l >> 4) * 4 + r;
#pragma unroll
        for (int ni = 0; ni < 4; ++ni) {
          const int col = n0 + wc * 64 + ni * 16 + (l & 15);
          const size_t ix = (size_t)row * 1024 + col;
          float v = acc[mi][ni][r];
          if (!pw) v += P[ix];
          P[ix] = v;
        }
      }
  }
#undef STG_A
#undef STG_B
#undef RDA
#undef RDB
#undef SYNC
#undef ENDPH
#undef VM6
#undef MM
#undef TILEBODY
}

// out = [p0 + p1 +] sum_e sg[n,e]*b2[e,:]   (float4-vectorized)
// NOTE: p0 may alias out (mid tier) -> no __restrict__ on p0/out.
template <bool WITHP>
__global__ void finalize_out(const float* p0,
                             const float* __restrict__ p1,
                             const float* __restrict__ sgate,
                             const float* __restrict__ b2,
                             float* out) {
  const int i = blockIdx.x * 256 + threadIdx.x;   // float4 index, 2M total
  const int n = i >> 8, c4 = i & 255;
  float4 a = make_float4(0.f, 0.f, 0.f, 0.f);
  if constexpr (WITHP) {
    const float4 u = ((const float4*)p0)[i];
    const float4 v = ((const float4*)p1)[i];
    a.x = u.x + v.x; a.y = u.y + v.y; a.z = u.z + v.z; a.w = u.w + v.w;
  }
  const float* sg = sgate + (size_t)n * 8;
#pragma unroll
  for (int e = 0; e < 8; ++e) {
    const float s = sg[e];
    const float4 bv = ((const float4*)(b2 + (size_t)e * 1024))[c4];
    a.x += s * bv.x; a.y += s * bv.y; a.z += s * bv.z; a.w += s * bv.w;
  }
  ((float4*)out)[i] = a;
}

// ---------------------------------------------------------------------------
// Fallback GEMM2 (round-2/3 proven pipeline): Out[8192x1024] += hh_e x w2t_e^T.
// BM=256,BN=128,BK=64, 3-buffer, vmcnt(6), 0-conflict swizzle. RMW epilogue.
// ---------------------------------------------------------------------------
__global__ __launch_bounds__(512, 2) void gemm_acc(
    const f16* __restrict__ A, const f16* __restrict__ Bt,
    float* __restrict__ Out, int N, int K, int gx) {
  __shared__ alignas(16) f16 lA[3 * 256 * 64];
  __shared__ alignas(16) f16 lB[3 * 128 * 64];
  const int tid = threadIdx.x;
  const int l = tid & 63, w = tid >> 6;
  const int wr = w >> 1, wc = w & 1;
  const int nwg = gridDim.x, cpx = nwg >> 3;
  const int lg = ((int)blockIdx.x & 7) * cpx + ((int)blockIdx.x >> 3);
  const int bx = lg % gx, by = lg / gx;
  const int m0 = by * 256, n0 = bx * 128;

  const int srow = tid >> 3;
  const int scol = (((tid & 7) ^ (srow & 7)) << 3);
  const f16* Ab = A + ((size_t)m0 + srow) * K + scol;
  const f16* Bb = Bt + ((size_t)n0 + srow) * K + scol;
  f16* const dA = &lA[w * 512];
  f16* const dB = &lB[w * 512];

  int aoff[4][2], boff[4][2];
#pragma unroll
  for (int f = 0; f < 4; ++f) {
    const int ar = wr * 64 + f * 16 + (l & 15);
    const int br = wc * 64 + f * 16 + (l & 15);
#pragma unroll
    for (int ks = 0; ks < 2; ++ks) {
      const int cb = ks * 64 + ((l >> 4) << 4);
      aoff[f][ks] = ar * 64 + ((cb ^ ((ar & 7) << 4)) >> 1);
      boff[f][ks] = br * 64 + ((cb ^ ((br & 7) << 4)) >> 1);
    }
  }
  f32x4 acc[4][4] = {};
  f16x8 b[4][2];
  f16x8 aA, aB, aC, aD;
#define STAGE_A(bs, t) do { \
    const f16* s_ = Ab + (size_t)(t) * 64; \
    gload_lds16(s_,                   dA + (bs) * 16384); \
    gload_lds16(s_ + (size_t)64 * K,  dA + (bs) * 16384 + 4096); \
    gload_lds16(s_ + (size_t)128 * K, dA + (bs) * 16384 + 8192); \
    gload_lds16(s_ + (size_t)192 * K, dA + (bs) * 16384 + 12288); \
  } while (0)
#define STAGE_B(bs, t) do { \
    const f16* s_ = Bb + (size_t)(t) * 64; \
    gload_lds16(s_,                   dB + (bs) * 8192); \
    gload_lds16(s_ + (size_t)64 * K,  dB + (bs) * 8192 + 4096); \
  } while (0)
#define LOAD_B(bs) do { \
    b[0][0] = *(const f16x8*)&lB[(bs) * 8192 + boff[0][0]]; \
    b[0][1] = *(const f16x8*)&lB[(bs) * 8192 + boff[0][1]]; \
    b[1][0] = *(const f16x8*)&lB[(bs) * 8192 + boff[1][0]]; \
    b[1][1] = *(const f16x8*)&lB[(bs) * 8192 + boff[1][1]]; \
    b[2][0] = *(const f16x8*)&lB[(bs) * 8192 + boff[2][0]]; \
    b[2][1] = *(const f16x8*)&lB[(bs) * 8192 + boff[2][1]]; \
    b[3][0] = *(const f16x8*)&lB[(bs) * 8192 + boff[3][0]]; \
    b[3][1] = *(const f16x8*)&lB[(bs) * 8192 + boff[3][1]]; \
  } while (0)
#define LOAD_A4(bs, m0_, m1_) do { \
    aA = *(const f16x8*)&lA[(bs) * 16384 + aoff[m0_][0]]; \
    aB = *(const f16x8*)&lA[(bs) * 16384 + aoff[m0_][1]]; \
    aC = *(const f16x8*)&lA[(bs) * 16384 + aoff[m1_][0]]; \
    aD = *(const f16x8*)&lA[(bs) * 16384 + aoff[m1_][1]]; \
  } while (0)
#define CLUSTER(m0_, m1_) do { \
    __builtin_amdgcn_s_setprio(1); \
    acc[m0_][0] = MFMAOP(aA, b[0][0], acc[m0_][0]); \
    acc[m0_][1] = MFMAOP(aA, b[1][0], acc[m0_][1]); \
    acc[m0_][2] = MFMAOP(aA, b[2][0], acc[m0_][2]); \
    acc[m0_][3] = MFMAOP(aA, b[3][0], acc[m0_][3]); \
    acc[m1_][0] = MFMAOP(aC, b[0][0], acc[m1_][0]); \
    acc[m1_][1] = MFMAOP(aC, b[1][0], acc[m1_][1]); \
    acc[m1_][2] = MFMAOP(aC, b[2][0], acc[m1_][2]); \
    acc[m1_][3] = MFMAOP(aC, b[3][0], acc[m1_][3]); \
    acc[m0_][0] = MFMAOP(aB, b[0][1], acc[m0_][0]); \
    acc[m0_][1] = MFMAOP(aB, b[1][1], acc[m0_][1]); \
    acc[m0_][2] = MFMAOP(aB, b[2][1], acc[m0_][2]); \
    acc[m0_][3] = MFMAOP(aB, b[3][1], acc[m0_][3]); \
    acc[m1_][0] = MFMAOP(aD, b[0][1], acc[m1_][0]); \
    acc[m1_][1] = MFMAOP(aD, b[1][1], acc[m1_][1]); \
    acc[m1_][2] = MFMAOP(aD, b[2][1], acc[m1_][2]); \
    acc[m1_][3] = MFMAOP(aD, b[3][1], acc[m1_][3]); \
    __builtin_amdgcn_s_setprio(0); \
  } while (0)
#define BAR() asm volatile("s_barrier" ::: "memory")
#define VMC6() asm volatile("s_waitcnt vmcnt(6)" ::: "memory")
  const int niter = K >> 7, ntiles = K >> 6;
  STAGE_A(0, 0); STAGE_B(0, 0);
  STAGE_A(1, 1); STAGE_B(1, 1);
  VMC6();
  BAR();
  int bp = 0, bq = 1, brr = 2;
  int t2 = 2, t3 = 3;
  for (int i = 0; i < niter; ++i) {
    LOAD_B(bp); LOAD_A4(bp, 0, 1);
    STAGE_A(brr, t2);
    BAR(); CLUSTER(0, 1); BAR();
    LOAD_A4(bp, 2, 3);
    STAGE_B(brr, t2);
    VMC6(); BAR(); CLUSTER(2, 3); BAR();
    LOAD_B(bq); LOAD_A4(bq, 0, 1);
    STAGE_A(bp, t3);
    BAR(); CLUSTER(0, 1); BAR();
    LOAD_A4(bq, 2, 3);
    STAGE_B(bp, t3);
    VMC6(); BAR(); CLUSTER(2, 3); BAR();
    const int tmp = bp; bp = brr; brr = bq; bq = tmp;
    t2 += 2; if (t2 >= ntiles) t2 -= ntiles;
    t3 += 2; if (t3 >= ntiles) t3 -= ntiles;
  }
  asm volatile("s_waitcnt vmcnt(0)" ::: "memory");
#pragma unroll
  for (int mi = 0; mi < 4; ++mi)
#pragma unroll
    for (int r = 0; r < 4; ++r) {
      const int row = m0 + wr * 64 + mi * 16 + (l >> 4) * 4 + r;
#pragma unroll
      for (int ni = 0; ni < 4; ++ni) {
        const int col = n0 + wc * 64 + ni * 16 + (l & 15);
        Out[(size_t)row * N + col] += acc[mi][ni][r];
      }
    }
#undef STAGE_A
#undef STAGE_B
#undef LOAD_B
#undef LOAD_A4
#undef CLUSTER
#undef BAR
#undef VMC6
}

extern "C" void kernel_launch(void* const* d_in, const int* in_sizes, int n_in,
                              void* d_out, int out_size, void* d_ws, size_t ws_size,
                              hipStream_t stream) {
  const float* x  = (const float*)d_in[0];
  const float* gw = (const float*)d_in[1];
  const float* gb = (const float*)d_in[2];
  const float* w1 = (const float*)d_in[3];
  const float* b1 = (const float*)d_in[4];
  const float* w2 = (const float*)d_in[5];
  const float* b2 = (const float*)d_in[6];
  float* out = (float*)d_out;

  char* ws = (char*)d_ws;
  float* sgate = (float*)(ws + OFF_SGATE);
  f16* xh  = (f16*)(ws + OFF_XH);
  f16* w1t = (f16*)(ws + OFF_W1T);
  f16* w2t = (f16*)(ws + OFF_W2T);
  f16* hhs = (f16*)(ws + OFF_HHS);
  float* p1 = (float*)(ws + OFF_P1);

  const bool mid = (ws_size >= NEED_MID);

  gate_kernel<<<NROWS / 4, 256, 0, stream>>>(x, gw, gb, sgate);
  cvt_x_kernel<<<(NROWS * DIN) / (256 * 4), 256, 0, stream>>>(x, xh);
  transpose_cvt<<<dim3(DHID / 32, DIN / 32, NEXP), dim3(32, 8), 0, stream>>>(w1, w1t, DIN, DHID);
  transpose_cvt<<<dim3(DOUT / 32, DHID / 32, NEXP), dim3(32, 8), 0, stream>>>(w2, w2t, DHID, DOUT);

  if (mid) {
    // GEMM1 8-phase per expert -> hh (sg*relu folded); GEMM2 8-phase
    // split-K=2: kh0 -> out, kh1 -> P1 (e==0 writes, else RMW accumulate).
    for (int e = 0; e < NEXP; ++e) {
      gemm8p<1><<<512, 512, 0, stream>>>(
          xh, DIN, w1t + (size_t)e * DHID * DIN, DIN, DIN / 64,
          b1 + (size_t)e * DHID, hhs, DHID,
          nullptr, nullptr, 0, sgate, e, DHID / 256);
      gemm8p<2><<<256, 512, 0, stream>>>(
          hhs, DHID, w2t + (size_t)e * DOUT * DHID, DHID, 2048 / 64,
          nullptr, nullptr, 0, out, p1, (e == 0) ? 1 : 0, nullptr, 0, DOUT / 256);
    }
    finalize_out<true><<<(NROWS * DOUT) / (256 * 4), 256, 0, stream>>>(
        out, p1, sgate, b2, out);
  } else {
    // fallback: bias pre-write, per-expert hh + RMW gemm_acc (proven)
    finalize_out<false><<<(NROWS * DOUT) / (256 * 4), 256, 0, stream>>>(
        nullptr, nullptr, sgate, b2, out);
    for (int e = 0; e < NEXP; ++e) {
      gemm8p<1><<<512, 512, 0, stream>>>(
          xh, DIN, w1t + (size_t)e * DHID * DIN, DIN, DIN / 64,
          b1 + (size_t)e * DHID, hhs, DHID,
          nullptr, nullptr, 0, sgate, e, DHID / 256);
      gemm_acc<<<256, 512, 0, stream>>>(hhs, w2t + (size_t)e * DOUT * DHID,
                                        out, DOUT, DHID, DOUT / 128);
    }
  }
}